// Round 8
// baseline (72.235 us; speedup 1.0000x reference)
//
#include <hip/hip_runtime.h>

#define NB 256
#define CLIP_LIM 1024              // max(int(4.0*65536/256),1)
#define HSTRIDE 264                // 256+8: adjacent sub-hists shift bank pattern by 8
#define PSTRIDE 9                  // packed u16-pair entries per bin (s=0..8), gcd(9,32)=1

typedef float f32x4 __attribute__((ext_vector_type(4)));

// ---------------- Kernel 1: LINEAR histogram pass (no bins output) ----------------
// 512 blocks x 1024 thr; 8 blocks per (b,ty) band; each block reads a contiguous 256KB span
// with REGULAR loads so img allocates in L3 (134MB < 256MB) and K2 re-reads it from L3.
// Aligned 64-quad wave reads lie in ONE tile column; wave w serves tx = w&7 ->
// wave-private sub-hists (parity split -> 32 tables). Partials written without atomics.
__global__ __launch_bounds__(1024) void clahe_hist(const float* __restrict__ img,
                                                   unsigned int* __restrict__ part) {
    const int blk  = blockIdx.x;         // 0..511
    const int tid  = threadIdx.x;
    const int sub  = ((tid >> 6) << 1) | (tid & 1);   // 0..31: wave*2 + lane parity

    __shared__ int h[32 * HSTRIDE];      // 33,792 B

    #pragma unroll
    for (int k = 0; k < 9; ++k) {
        const int idx = tid + k * 1024;
        if (idx < 32 * HSTRIDE) h[idx] = 0;
    }
    __syncthreads();

    const size_t B0 = (size_t)blk * 16384;    // base quad index (band*131072 + j*16384)
    int* hw = &h[sub * HSTRIDE];

    #pragma unroll
    for (int k = 0; k < 16; ++k) {
        const size_t g = B0 + k * 1024 + tid;           // image-linear quad index
        const f32x4 v = *reinterpret_cast<const f32x4*>(img + g * 4);   // L3-allocating
        const int b0 = (int)fminf(fmaxf(v.x, 0.f), 255.f);
        const int b1 = (int)fminf(fmaxf(v.y, 0.f), 255.f);
        const int b2 = (int)fminf(fmaxf(v.z, 0.f), 255.f);
        const int b3 = (int)fminf(fmaxf(v.w, 0.f), 255.f);
        atomicAdd(&hw[b0], 1);
        atomicAdd(&hw[b1], 1);
        atomicAdd(&hw[b2], 1);
        atomicAdd(&hw[b3], 1);
    }
    __syncthreads();

    // write partials: 8 tile-columns x 256 bins; tables for tx: {2tx,2tx+1,2tx+16,2tx+17}
    #pragma unroll
    for (int e = tid; e < 2048; e += 1024) {
        const int tx = e >> 8;
        const int bn = e & 255;
        const int s = h[(2 * tx) * HSTRIDE + bn] + h[(2 * tx + 1) * HSTRIDE + bn] +
                      h[(2 * tx + 16) * HSTRIDE + bn] + h[(2 * tx + 17) * HSTRIDE + bn];
        part[(size_t)blk * 2048 + e] = (unsigned int)s;          // coalesced
    }
}

// ---------------- Kernel 1b: reduce partials -> clip/redistribute -> scan -> LUT ----------------
__global__ __launch_bounds__(256) void clahe_lut(const unsigned int* __restrict__ part,
                                                 float* __restrict__ lut) {
    const int t    = blockIdx.x;         // tile = band*8 + tx = b*64 + ty*8 + tx
    const int band = t >> 3;
    const int tx   = t & 7;
    const int tid  = threadIdx.x;        // bin

    __shared__ int c[NB];
    __shared__ int s_excess;
    if (tid == 0) s_excess = 0;
    __syncthreads();

    int sum = 0;
    #pragma unroll
    for (int j = 0; j < 8; ++j)
        sum += (int)part[(size_t)(band * 8 + j) * 2048 + tx * 256 + tid];

    const int clipped0 = min(sum, CLIP_LIM);
    atomicAdd(&s_excess, sum - clipped0);
    __syncthreads();

    const int excess   = s_excess;
    const int add      = excess >> 8;
    const int residual = excess & 255;
    int step = 256 / (residual > 0 ? residual : 1);
    if (step < 1) step = 1;
    c[tid] = clipped0 + add + ((residual > 0 && (tid % step) == 0) ? 1 : 0);
    __syncthreads();

    // inclusive Hillis-Steele scan over 256 bins
    #pragma unroll
    for (int off = 1; off < NB; off <<= 1) {
        const int v = (tid >= off) ? c[tid - off] : 0;
        __syncthreads();
        c[tid] += v;
        __syncthreads();
    }

    float lv = rintf((float)c[tid] * (255.0f / 65536.0f));   // exact; RTE == jnp.round
    lut[t * NB + tid] = fminf(fmaxf(lv, 0.f), 255.f);
}

// ---------------- Kernel 2: bilinear LUT apply, bins recomputed from L3-resident img ----------------
// Block = (image, even row pair); packed fixed-point 8.8 tables; ONE ds_read_b32 per pixel.
// bins = (int)clip(img,0,255) recomputed inline (exact ints -> identical to K1's view).
// All f32 arithmetic exact (integers x k/256 weights, numerators < 2^24) -> bit-exact vs ref.
__global__ __launch_bounds__(256, 8) void clahe_apply(const float* __restrict__ img,
                                                      const float* __restrict__ lut,
                                                      float* __restrict__ out) {
    const int bi  = blockIdx.x;
    const int b   = bi >> 10;
    const int y0  = (bi & 1023) * 2;     // even row pair; never straddles a y-segment boundary
    const int tid = threadIdx.x;

    __shared__ unsigned int T[2 * NB * PSTRIDE];   // 18,432 B

    {   // ---- build packed y-blended tables for both rows (tid == bin)
        const float yf  = (float)y0 * (1.0f / 256.0f) - 0.5f;
        const float y1f = floorf(yf);
        const int y1 = min(max((int)y1f, 0), 7);
        const int y2 = min(max((int)y1f + 1, 0), 7);
        const float* lb = lut + ((size_t)b << 14);
        float la[8], lc[8];
        #pragma unroll
        for (int xc = 0; xc < 8; ++xc) {
            la[xc] = lb[(y1 * 8 + xc) * NB + tid];
            lc[xc] = lb[(y2 * 8 + xc) * NB + tid];
        }
        #pragma unroll
        for (int r = 0; r < 2; ++r) {
            const float q = (float)((y0 + r + 128) & 255);   // ya*256, integer
            float tv[10];
            #pragma unroll
            for (int k = 0; k < 10; ++k) {
                const int kc = (k == 0) ? 0 : ((k - 1 > 7) ? 7 : k - 1);
                tv[k] = la[kc] * (256.0f - q) + lc[kc] * q;  // exact integer <= 65280
            }
            unsigned int* Tr = &T[r * NB * PSTRIDE + tid * PSTRIDE];
            #pragma unroll
            for (int s = 0; s < 9; ++s)
                Tr[s] = (unsigned int)tv[s] | ((unsigned int)tv[s + 1] << 16);
        }
    }
    __syncthreads();

    const size_t imgbase = ((size_t)b << 22) + (size_t)y0 * 2048;
    #pragma unroll
    for (int it = 0; it < 4; ++it) {
        const int r = it >> 1;
        const int i = (it & 1) * 256 + tid;          // float4-word index in row, 0..511
        const size_t prow = imgbase + (size_t)r * 2048;
        const f32x4 v = *reinterpret_cast<const f32x4*>(img + prow + i * 4);  // L3 hit
        const int bn4[4] = { (int)fminf(fmaxf(v.x, 0.f), 255.f),
                             (int)fminf(fmaxf(v.y, 0.f), 255.f),
                             (int)fminf(fmaxf(v.z, 0.f), 255.f),
                             (int)fminf(fmaxf(v.w, 0.f), 255.f) };
        const unsigned int* Tr = &T[r * NB * PSTRIDE];
        const int x   = i * 4;
        const int s   = (x + 128) >> 8;              // 0..8, constant within quad
        const float xa0 = (float)((x + 128) & 255);  // numerator; no wrap within j=0..3
        float res[4];
        #pragma unroll
        for (int j = 0; j < 4; ++j) {
            const unsigned int u = Tr[bn4[j] * PSTRIDE + s];  // one ds_read_b32
            const float a  = (float)(u & 0xFFFFu);            // left*256 (exact int)
            const float bb = (float)(u >> 16);                // right*256 (exact int)
            const float xa = (xa0 + (float)j) * (1.0f / 256.0f);
            const float vv = a + (bb - a) * xa;               // exact, = result*256
            res[j] = fminf(fmaxf(rintf(vv * (1.0f / 256.0f)), 0.f), 255.f);
        }
        const f32x4 o = { res[0], res[1], res[2], res[3] };
        __builtin_nontemporal_store(o, reinterpret_cast<f32x4*>(out + prow + i * 4));
    }
}

extern "C" void kernel_launch(void* const* d_in, const int* in_sizes, int n_in,
                              void* d_out, int out_size, void* d_ws, size_t ws_size,
                              hipStream_t stream) {
    const float* img = (const float*)d_in[0];
    float* out = (float*)d_out;
    float* lut = (float*)d_ws;                                   // 512 KiB
    unsigned int* part = (unsigned int*)((char*)d_ws + 512 * 1024);   // 4 MB

    clahe_hist<<<512, 1024, 0, stream>>>(img, part);
    clahe_lut<<<512, 256, 0, stream>>>(part, lut);
    clahe_apply<<<8 * 1024, 256, 0, stream>>>(img, lut, out);
}